// Round 12
// baseline (139.149 us; speedup 1.0000x reference)
//
#include <hip/hip_runtime.h>
#include <stdint.h>

typedef float  f32x4 __attribute__((ext_vector_type(4)));
typedef short  s16x8 __attribute__((ext_vector_type(8)));
typedef unsigned short u16;

#define GN_EPS 1e-5f

// ws layout (bytes):
//   0       gsum[128] f32
//   512     gsqs[128] f32
//   9216    tvec[512] f32
//   16384   wn[512*1024] bf16 (1 MiB)
//   2097152 yt[16384*1024] bf16 (32 MiB)   -- y transposed: [hw][c]

__device__ __forceinline__ u16 f2bf(float f) {
  unsigned u = __float_as_uint(f);
  u += 0x7fffu + ((u >> 16) & 1u);
  return (u16)(u >> 16);
}

__device__ __forceinline__ float wave_red_sum(float v) {
#pragma unroll
  for (int off = 32; off > 0; off >>= 1) v += __shfl_down(v, off, 64);
  return v;
}

__device__ __forceinline__ void gload16(const void* g, void* l) {
  __builtin_amdgcn_global_load_lds(
      (const __attribute__((address_space(1))) uint32_t*)(uintptr_t)g,
      (__attribute__((address_space(3))) uint32_t*)(uintptr_t)l,
      16, 0, 0);
}

// ---------------- Phase A: Haar + y_t(bf16) + group partial stats ----------------
__global__ __launch_bounds__(256) void haar_kernel(
    const float* __restrict__ x, u16* __restrict__ yt,
    float* __restrict__ gsum, float* __restrict__ gsqs)
{
  const int t    = threadIdx.x;
  const int cti  = t & 7;
  const int hwi  = t >> 3;                      // 0..31
  const int hw0  = blockIdx.x * 64 + hwi * 2;   // even hw; pair {hw0, hw0+1}
  const int h    = hw0 >> 7, w = hw0 & 127;
  const int cin0 = blockIdx.y * 64 + cti * 8;   // 8 input channels

  float sv[4] = {0.f,0.f,0.f,0.f}, qv[4] = {0.f,0.f,0.f,0.f};
  s16x8 ov[2][4];
  f32x4 R0[8], R1[8];

  const float* xb = x + ((size_t)cin0 << 16) + (size_t)(2*h)*256 + (size_t)(2*w);
#pragma unroll
  for (int j = 0; j < 8; ++j) {
    const float* xp = xb + ((size_t)j << 16);
    R0[j] = *(const f32x4*)(xp);
    R1[j] = *(const f32x4*)(xp + 256);
  }
#pragma unroll
  for (int j = 0; j < 8; ++j) {
    f32x4 r0 = R0[j], r1 = R1[j];
#pragma unroll
    for (int p = 0; p < 2; ++p) {
      float x00 = p ? r0.z : r0.x;
      float x01 = p ? r0.w : r0.y;
      float x10 = p ? r1.z : r1.x;
      float x11 = p ? r1.w : r1.y;
      float LL = 0.5f*( x00 + x01 + x10 + x11);
      float HL = 0.5f*(-x00 - x01 + x10 + x11);
      float LH = 0.5f*(-x00 + x01 - x10 + x11);
      float HH = 0.5f*( x00 - x01 - x10 + x11);
      ov[p][0][j] = (short)f2bf(LL);
      ov[p][1][j] = (short)f2bf(HL);
      ov[p][2][j] = (short)f2bf(LH);
      ov[p][3][j] = (short)f2bf(HH);
      sv[0] += LL; qv[0] += LL*LL;
      sv[1] += HL; qv[1] += HL*HL;
      sv[2] += LH; qv[2] += LH*LH;
      sv[3] += HH; qv[3] += HH*HH;
    }
  }

  u16* yb = yt + (size_t)hw0 * 1024 + cin0;
#pragma unroll
  for (int p = 0; p < 2; ++p)
#pragma unroll
    for (int b = 0; b < 4; ++b)
      *(s16x8*)(yb + p*1024 + b*256) = ov[p][b];

#pragma unroll
  for (int k = 0; k < 4; ++k) {
#pragma unroll
    for (int msk = 8; msk < 64; msk <<= 1) {
      sv[k] += __shfl_xor(sv[k], msk, 64);
      qv[k] += __shfl_xor(qv[k], msk, 64);
    }
  }
  __shared__ float red[4][8][8];
  const int lane = t & 63, wv = t >> 6;
  if (lane < 8) {
#pragma unroll
    for (int k = 0; k < 4; ++k) {
      red[wv][lane][k]     = sv[k];
      red[wv][lane][4 + k] = qv[k];
    }
  }
  __syncthreads();
  if (t < 64) {
    int c8 = t & 7, vi = t >> 3;
    float tot = red[0][c8][vi] + red[1][c8][vi] + red[2][c8][vi] + red[3][c8][vi];
    int b = vi & 3;
    int g = b*32 + blockIdx.y*8 + c8;
    if (vi < 4) atomicAdd(&gsum[g], tot);
    else        atomicAdd(&gsqs[g], tot);
  }
}

// ---------------- Phase B: stats + fold a_c into weights (bf16) + bias vector t ----------------
__global__ __launch_bounds__(256) void wprep_kernel(
    const float* __restrict__ wproj, const float* __restrict__ gsum,
    const float* __restrict__ gsqs, const float* __restrict__ scale,
    const float* __restrict__ bias, u16* __restrict__ wn, float* __restrict__ tvec)
{
  const int o = blockIdx.x;
  const int t = threadIdx.x;
  const float invN = 1.0f / 131072.0f;
  float acc = 0.f;
#pragma unroll
  for (int j = 0; j < 4; ++j) {
    int c = j*256 + t;
    int g = c >> 3;
    float mean = gsum[g] * invN;
    float var  = gsqs[g] * invN - mean * mean;
    float inv  = rsqrtf(var + GN_EPS);
    float a = scale[c] * inv;
    float b = bias[c] - mean * a;
    float wv = wproj[o*1024 + c];
    wn[o*1024 + c] = f2bf(wv * a);
    acc += wv * b;
  }
  acc = wave_red_sum(acc);
  __shared__ float red[4];
  int lane = t & 63, wvi = t >> 6;
  if (lane == 0) red[wvi] = acc;
  __syncthreads();
  if (t == 0) tvec[o] = red[0] + red[1] + red[2] + red[3];
}

// ---------------- Phase C: GEMM out[o][hw] = relu(sum_c wn[o][c]*yt[hw][c] + t[o]) ----------------
// Phase-split pipeline (T3+T4): BM=256 BN=128 BK=64, 512 thr (8 waves of 64x64 --
// per-wave math identical to the proven 128^2 kernel), 3-buffer LDS (144 KB, 1 blk/CU,
// grid=256 = 1/CU). 2 phases/K-step, each {8 ds_read || 3 gload_lds || barrier ||
// setprio(1) 16 MFMA setprio(0)}; counted vmcnt(6) at K-step boundary -- 2 tiles
// always in flight, never drained in the loop (drain only at tail).
// Buffer lifetime: tile t's buffer is overwritten by loads for t+3, issued after the
// t->t+1 boundary barrier; all reads of it are lgkm-complete before that barrier.
#define BM 256
#define BN 128
#define BK 64
#define NT 16

#define BAR() asm volatile("s_barrier" ::: "memory")

__global__ __launch_bounds__(512, 2) void gemm_kernel(
    const u16* __restrict__ A,   // wn [512][1024]  row-major, K contiguous
    const u16* __restrict__ B,   // yt [16384][1024] row-major, K contiguous
    const float* __restrict__ tvec,
    float* __restrict__ out)     // [512][16384]
{
  __shared__ __align__(1024) u16 As[3][BM*BK];  // 3 x 32 KiB, XOR-swizzled rows
  __shared__ __align__(1024) u16 Bs[3][BN*BK];  // 3 x 16 KiB

  const int tid  = threadIdx.x;
  const int lane = tid & 63, wave = tid >> 6;   // 8 waves

  // XCD-chunked, m-fast swizzle (nwg=256, 256%8==0 -> bijective)
  const int bid = blockIdx.x;                   // 0..255
  const int cid = (bid & 7) * 32 + (bid >> 3);
  const int m0 = (cid & 1) * BM;
  const int n0 = (cid >> 1) * BN;

  const int wm = wave >> 1, wn_ = wave & 1;     // 4M x 2N waves of 64x64
  const int g = lane >> 4, r = lane & 15;

  f32x4 acc[4][4];
#pragma unroll
  for (int i = 0; i < 4; ++i)
#pragma unroll
    for (int j = 0; j < 4; ++j) acc[i][j] = (f32x4)(0.f);

  // staging geometry: A = 4 chunks of 8 KB, B = 2 chunks of 8 KB; 16 B/thread each.
  // source pre-inverse-swizzled so LDS[row][off] = G[row][off ^ ((row&7)<<4)].
  int arow[4], aoff[4], brow[2], boff[2];
#pragma unroll
  for (int ci = 0; ci < 4; ++ci) {
    int lin = ci*8192 + tid*16;
    arow[ci] = lin >> 7;
    aoff[ci] = (lin & 127) ^ ((arow[ci] & 7) << 4);
  }
#pragma unroll
  for (int ci = 0; ci < 2; ++ci) {
    int lin = ci*8192 + tid*16;
    brow[ci] = lin >> 7;
    boff[ci] = (lin & 127) ^ ((brow[ci] & 7) << 4);
  }

  auto LOADA = [&](int buf, int k0, int ci) {
    gload16((const char*)(A + (size_t)(m0 + arow[ci])*1024 + k0) + aoff[ci],
            (char*)As[buf] + ci*8192 + tid*16);
  };
  auto LOADB = [&](int buf, int k0, int ci) {
    gload16((const char*)(B + (size_t)(n0 + brow[ci])*1024 + k0) + boff[ci],
            (char*)Bs[buf] + ci*8192 + tid*16);
  };

  // prologue: tiles 0 and 1 fully issued (12 loads/thread in flight)
#pragma unroll
  for (int ci = 0; ci < 4; ++ci) LOADA(0, 0, ci);
#pragma unroll
  for (int ci = 0; ci < 2; ++ci) LOADB(0, 0, ci);
#pragma unroll
  for (int ci = 0; ci < 4; ++ci) LOADA(1, BK, ci);
#pragma unroll
  for (int ci = 0; ci < 2; ++ci) LOADB(1, BK, ci);
  asm volatile("s_waitcnt vmcnt(6)" ::: "memory");  // tile 0 landed; tile 1 in flight
  BAR();

#pragma unroll 1
  for (int t = 0; t < NT; ++t) {
    const int buf = t % 3;
    const int nxt = (t + 2) % 3;
    const int kN  = (t + 2) * BK;
    const bool pre = (t + 2 < NT);

    // ---- phase 0 (kk=0) ----
    {
      s16x8 av[4], bv[4];
      const int kb = g*16;
#pragma unroll
      for (int m = 0; m < 4; ++m) {
        int row = wm*64 + m*16 + r;
        av[m] = *(const s16x8*)((const char*)As[buf] + row*128 + (kb ^ ((row & 7) << 4)));
      }
#pragma unroll
      for (int n = 0; n < 4; ++n) {
        int row = wn_*64 + n*16 + r;
        bv[n] = *(const s16x8*)((const char*)Bs[buf] + row*128 + (kb ^ ((row & 7) << 4)));
      }
      if (pre) { LOADA(nxt, kN, 0); LOADA(nxt, kN, 1); LOADA(nxt, kN, 2); }
      BAR();
      __builtin_amdgcn_s_setprio(1);
#pragma unroll
      for (int m = 0; m < 4; ++m)
#pragma unroll
        for (int n = 0; n < 4; ++n)
          acc[m][n] = __builtin_amdgcn_mfma_f32_16x16x32_bf16(av[m], bv[n], acc[m][n], 0, 0, 0);
      __builtin_amdgcn_s_setprio(0);
      __builtin_amdgcn_sched_barrier(0);
      BAR();
    }
    // ---- phase 1 (kk=1) ----
    {
      s16x8 av[4], bv[4];
      const int kb = 64 + g*16;
#pragma unroll
      for (int m = 0; m < 4; ++m) {
        int row = wm*64 + m*16 + r;
        av[m] = *(const s16x8*)((const char*)As[buf] + row*128 + (kb ^ ((row & 7) << 4)));
      }
#pragma unroll
      for (int n = 0; n < 4; ++n) {
        int row = wn_*64 + n*16 + r;
        bv[n] = *(const s16x8*)((const char*)Bs[buf] + row*128 + (kb ^ ((row & 7) << 4)));
      }
      if (pre) { LOADA(nxt, kN, 3); LOADB(nxt, kN, 0); LOADB(nxt, kN, 1); }
      BAR();
      __builtin_amdgcn_s_setprio(1);
#pragma unroll
      for (int m = 0; m < 4; ++m)
#pragma unroll
        for (int n = 0; n < 4; ++n)
          acc[m][n] = __builtin_amdgcn_mfma_f32_16x16x32_bf16(av[m], bv[n], acc[m][n], 0, 0, 0);
      __builtin_amdgcn_s_setprio(0);
      __builtin_amdgcn_sched_barrier(0);
      // boundary: tile t+1 must be landed before next step's ds_reads; keep t+2 in flight
      if (t <= NT - 3)      asm volatile("s_waitcnt vmcnt(6)" ::: "memory");
      else if (t == NT - 2) asm volatile("s_waitcnt vmcnt(0)" ::: "memory");
      BAR();
    }
  }

  // ---- epilogue: +bias, ReLU, store ----
#pragma unroll
  for (int m = 0; m < 4; ++m) {
#pragma unroll
    for (int rr = 0; rr < 4; ++rr) {
      int o = m0 + wm*64 + m*16 + g*4 + rr;
      float tv = tvec[o];
      float* op = out + (size_t)o*16384 + n0 + wn_*64 + r;
#pragma unroll
      for (int n = 0; n < 4; ++n) {
        float v = acc[m][n][rr] + tv;
        op[n*16] = v > 0.f ? v : 0.f;
      }
    }
  }
}

extern "C" void kernel_launch(void* const* d_in, const int* in_sizes, int n_in,
                              void* d_out, int out_size, void* d_ws, size_t ws_size,
                              hipStream_t stream)
{
  const float* x  = (const float*)d_in[0];
  const float* sc = (const float*)d_in[1];
  const float* bi = (const float*)d_in[2];
  const float* wp = (const float*)d_in[3];
  float* out = (float*)d_out;

  char* ws = (char*)d_ws;
  float* gsum = (float*)(ws + 0);
  float* gsqs = (float*)(ws + 512);
  float* tv   = (float*)(ws + 9216);
  u16*   wn   = (u16*)(ws + 16384);
  u16*   yt   = (u16*)(ws + 2097152);

  hipMemsetAsync(ws, 0, 1024, stream);  // zero gsum+gsqs (ws is poisoned each call)
  hipLaunchKernelGGL(haar_kernel,  dim3(256, 4), dim3(256), 0, stream, x, yt, gsum, gsqs);
  hipLaunchKernelGGL(wprep_kernel, dim3(512),    dim3(256), 0, stream, wp, gsum, gsqs, sc, bi, wn, tv);
  hipLaunchKernelGGL(gemm_kernel,  dim3(256),    dim3(512), 0, stream, wn, yt, tv, out);
}